// Round 2
// baseline (725.149 us; speedup 1.0000x reference)
//
#include <hip/hip_runtime.h>
#include <stdint.h>

#define NV 200000
#define BN_EPS 1e-5f

typedef short bf16x8 __attribute__((ext_vector_type(8)));
typedef float f32x4 __attribute__((ext_vector_type(4)));

__device__ inline unsigned short f2bf(float x) {
  union { float f; uint32_t u; } c; c.f = x;
  uint32_t r = c.u + 0x7fffu + ((c.u >> 16) & 1u);
  return (unsigned short)(r >> 16);
}
__device__ inline float bf2f(unsigned short u) {
  union { uint32_t u; float f; } c; c.u = ((uint32_t)u) << 16;
  return c.f;
}

__device__ inline void gload_lds16(const void* g, void* l) {
  __builtin_amdgcn_global_load_lds(
      (const __attribute__((address_space(1))) unsigned int*)(g),
      (__attribute__((address_space(3))) unsigned int*)(l), 16, 0, 0);
}

__device__ inline void store_out(unsigned short* p, float x) { *p = f2bf(x); }
__device__ inline void store_out(float* p, float x) { *p = x; }

// ---------------------------------------------------------------------------
// Gather-GEMM with MFMA. A is (NV+1) x K bf16 (row NV = zero sentinel).
// Wpack layout: [NTAPS][K/32][8 colfrag][64 lane][8] bf16  (fragment-native)
// out[i] = sum_taps A[nbr(tap,i)] @ W[tap],  N=128 output cols.
// Also accumulates per-column sum / sumsq (for BN) via atomics.
// ---------------------------------------------------------------------------
template <int K, int NTAPS, bool GATHER, typename OUT>
__global__ __launch_bounds__(256, 2) void conv_mfma(
    const unsigned short* __restrict__ Apad, const int* __restrict__ nbr,
    const unsigned short* __restrict__ Wpack, OUT* __restrict__ outp,
    float* __restrict__ ssum, float* __restrict__ ssq) {
  constexpr int S = K / 32;
  constexpr int TAPBYTES = S * 8 * 64 * 16;  // 16KB (K=64) / 32KB (K=128)
  __shared__ unsigned short Wlds[TAPBYTES / 2];
  __shared__ float sred[4][128];

  const int tid = threadIdx.x;
  const int w = tid >> 6;
  const int l = tid & 63;
  const int l15 = l & 15;
  const int lhi = l >> 4;
  const int rowbase = blockIdx.x * 256 + w * 64;

  f32x4 acc[4][8];
#pragma unroll
  for (int rf = 0; rf < 4; ++rf)
#pragma unroll
    for (int cf = 0; cf < 8; ++cf) acc[rf][cf] = f32x4{0.f, 0.f, 0.f, 0.f};

  for (int tap = 0; tap < NTAPS; ++tap) {
    // stage this tap's packed W into LDS; each wave stages a quarter
    const char* wsrc = (const char*)Wpack + (size_t)tap * TAPBYTES;
    const int base = w * (TAPBYTES / 4);
#pragma unroll
    for (int i = 0; i < TAPBYTES / 4096; ++i) {
      const int off = base + i * 1024;
      gload_lds16(wsrc + off + l * 16, (char*)Wlds + off);
    }
    // neighbor row indices for this tap (overlaps staging)
    int ridx[4];
#pragma unroll
    for (int rf = 0; rf < 4; ++rf) {
      const int row = rowbase + rf * 16 + l15;
      int r = NV;  // zero sentinel
      if (row < NV) r = GATHER ? nbr[tap * NV + row] : row;
      ridx[rf] = r;
    }
    __syncthreads();  // staging complete (drains vmcnt)
#pragma unroll
    for (int s = 0; s < S; ++s) {
      bf16x8 b[8];
#pragma unroll
      for (int cf = 0; cf < 8; ++cf)
        b[cf] = *(const bf16x8*)&Wlds[((s * 8 + cf) * 64 + l) * 8];
#pragma unroll
      for (int rf = 0; rf < 4; ++rf) {
        const bf16x8 a =
            *(const bf16x8*)(Apad + (size_t)ridx[rf] * K + s * 32 + lhi * 8);
#pragma unroll
        for (int cf = 0; cf < 8; ++cf)
          acc[rf][cf] =
              __builtin_amdgcn_mfma_f32_16x16x32_bf16(a, b[cf], acc[rf][cf], 0, 0, 0);
      }
    }
    __syncthreads();  // all waves done reading before next tap overwrites LDS
  }

  // ---- per-column BN statistics (padded rows contribute exact zeros) ----
  float psum[8], psq[8];
#pragma unroll
  for (int cf = 0; cf < 8; ++cf) {
    float s = 0.f, q = 0.f;
#pragma unroll
    for (int rf = 0; rf < 4; ++rf)
#pragma unroll
      for (int v = 0; v < 4; ++v) {
        const float x = acc[rf][cf][v];
        s += x;
        q += x * x;
      }
    psum[cf] = s;
    psq[cf] = q;
  }
#pragma unroll
  for (int cf = 0; cf < 8; ++cf) {
    psum[cf] += __shfl_xor(psum[cf], 16);
    psum[cf] += __shfl_xor(psum[cf], 32);
    psq[cf] += __shfl_xor(psq[cf], 16);
    psq[cf] += __shfl_xor(psq[cf], 32);
  }
  if (l < 16) {
#pragma unroll
    for (int cf = 0; cf < 8; ++cf) sred[w][cf * 16 + l] = psum[cf];
  }
  __syncthreads();
  if (tid < 128)
    atomicAdd(&ssum[tid], sred[0][tid] + sred[1][tid] + sred[2][tid] + sred[3][tid]);
  __syncthreads();
  if (l < 16) {
#pragma unroll
    for (int cf = 0; cf < 8; ++cf) sred[w][cf * 16 + l] = psq[cf];
  }
  __syncthreads();
  if (tid < 128)
    atomicAdd(&ssq[tid], sred[0][tid] + sred[1][tid] + sred[2][tid] + sred[3][tid]);

  // ---- store raw conv output ----
#pragma unroll
  for (int rf = 0; rf < 4; ++rf) {
#pragma unroll
    for (int v = 0; v < 4; ++v) {
      const int row = rowbase + rf * 16 + lhi * 4 + v;
      if (row < NV) {
#pragma unroll
        for (int cf = 0; cf < 8; ++cf)
          store_out(&outp[(size_t)row * 128 + cf * 16 + l15], acc[rf][cf][v]);
      }
    }
  }
}

// ---------------------------------------------------------------------------
// Weight packing: W [taps][K][128] fp32 -> fragment-native bf16 pack.
// dest e = (((tap*S + s)*8 + cf)*64 + l)*8 + j
// src  = W[tap][s*32 + (l>>4)*8 + j][cf*16 + (l&15)]
// ---------------------------------------------------------------------------
__global__ void pack_w_kernel(const float* __restrict__ W,
                              unsigned short* __restrict__ o, int sshift,
                              int total) {
  const int e = blockIdx.x * blockDim.x + threadIdx.x;
  if (e >= total) return;
  const int j = e & 7;
  const int l = (e >> 3) & 63;
  const int cf = (e >> 9) & 7;
  const int ts = e >> 12;
  const int S = 1 << sshift;
  const int s = ts & (S - 1);
  const int tap = ts >> sshift;
  const int kk = s * 32 + (l >> 4) * 8 + j;
  const int col = cf * 16 + (l & 15);
  o[e] = f2bf(W[((size_t)tap * (S * 32) + kk) * 128 + col]);
}

__global__ void feats_to_bf16(const float* __restrict__ f,
                              unsigned short* __restrict__ o) {
  const int i = blockIdx.x * blockDim.x + threadIdx.x;  // (NV+1)*16 vec4 groups
  if (i >= (NV + 1) * 16) return;
  const int row = i >> 4;
  const int c = (i & 15) * 4;
  ushort4 ov;
  if (row < NV) {
    const float4 v = *(const float4*)(f + (size_t)row * 64 + c);
    ov.x = f2bf(v.x);
    ov.y = f2bf(v.y);
    ov.z = f2bf(v.z);
    ov.w = f2bf(v.w);
  } else {
    ov = make_ushort4(0, 0, 0, 0);
  }
  *(ushort4*)(o + (size_t)row * 64 + c) = ov;
}

__global__ void zero_stats(float* st) {
  const int t = blockIdx.x * 256 + threadIdx.x;
  if (t < 768) st[t] = 0.f;
}

// stats layout (floats): 0 s1sum | 128 s1sq | 256 sksum | 384 sksq
//                        512 s2sum | 640 s2sq | 768 sc1 | 896 bi1
//                        1024 scsk | 1152 bisk | 1280 sc2 | 1408 bi2
__global__ void finalize1(float* st, const float* g1, const float* b1,
                          const float* gsk, const float* bsk) {
  const float invN = 1.0f / NV;
  const int t = threadIdx.x;
  if (t < 128) {
    const float m = st[t] * invN;
    const float v = st[128 + t] * invN - m * m;
    const float sc = g1[t] * rsqrtf(v + BN_EPS);
    st[768 + t] = sc;
    st[896 + t] = b1[t] - m * sc;
  } else {
    const int c = t - 128;
    const float m = st[256 + c] * invN;
    const float v = st[384 + c] * invN - m * m;
    const float sc = gsk[c] * rsqrtf(v + BN_EPS);
    st[1024 + c] = sc;
    st[1152 + c] = bsk[c] - m * sc;
  }
}

__global__ void finalize2(float* st, const float* g2, const float* b2) {
  const float invN = 1.0f / NV;
  const int c = threadIdx.x;
  const float m = st[512 + c] * invN;
  const float v = st[640 + c] * invN - m * m;
  const float sc = g2[c] * rsqrtf(v + BN_EPS);
  st[1280 + c] = sc;
  st[1408 + c] = b2[c] - m * sc;
}

__global__ void bn_to_bf16(const unsigned short* __restrict__ raw,
                           const float* __restrict__ scale,
                           const float* __restrict__ bias,
                           unsigned short* __restrict__ outp) {
  const int i = blockIdx.x * blockDim.x + threadIdx.x;  // (NV+1)*32
  if (i >= (NV + 1) * 32) return;
  const int row = i >> 5;
  const int c = (i & 31) * 4;
  ushort4 ov;
  if (row < NV) {
    const ushort4 rv = *(const ushort4*)(raw + (size_t)row * 128 + c);
    ov.x = f2bf(bf2f(rv.x) * scale[c + 0] + bias[c + 0]);
    ov.y = f2bf(bf2f(rv.y) * scale[c + 1] + bias[c + 1]);
    ov.z = f2bf(bf2f(rv.z) * scale[c + 2] + bias[c + 2]);
    ov.w = f2bf(bf2f(rv.w) * scale[c + 3] + bias[c + 3]);
  } else {
    ov = make_ushort4(0, 0, 0, 0);  // sentinel row for conv2 gathers
  }
  *(ushort4*)(outp + (size_t)row * 128 + c) = ov;
}

__global__ void final_kernel(float* __restrict__ res,
                             const unsigned short* __restrict__ sk,
                             const float* __restrict__ st) {
  const int i = blockIdx.x * blockDim.x + threadIdx.x;  // NV*32
  if (i >= NV * 32) return;
  const int row = i >> 5;
  const int c = (i & 31) * 4;
  const float* s2 = st + 1280;
  const float* b2 = st + 1408;
  const float* ss = st + 1024;
  const float* bs = st + 1152;
  const float4 r = *(const float4*)(res + (size_t)row * 128 + c);
  const ushort4 kv = *(const ushort4*)(sk + (size_t)row * 128 + c);
  float4 o;
  o.x = fmaxf(0.f, r.x * s2[c + 0] + b2[c + 0] + bf2f(kv.x) * ss[c + 0] + bs[c + 0]);
  o.y = fmaxf(0.f, r.y * s2[c + 1] + b2[c + 1] + bf2f(kv.y) * ss[c + 1] + bs[c + 1]);
  o.z = fmaxf(0.f, r.z * s2[c + 2] + b2[c + 2] + bf2f(kv.z) * ss[c + 2] + bs[c + 2]);
  o.w = fmaxf(0.f, r.w * s2[c + 3] + b2[c + 3] + bf2f(kv.w) * ss[c + 3] + bs[c + 3]);
  *(float4*)(res + (size_t)row * 128 + c) = o;
}

extern "C" void kernel_launch(void* const* d_in, const int* in_sizes, int n_in,
                              void* d_out, int out_size, void* d_ws,
                              size_t ws_size, hipStream_t stream) {
  const float* feats = (const float*)d_in[0];
  const int* nbr = (const int*)d_in[1];
  const float* W1 = (const float*)d_in[2];
  const float* g1 = (const float*)d_in[3];
  const float* b1 = (const float*)d_in[4];
  const float* W2 = (const float*)d_in[5];
  const float* g2 = (const float*)d_in[6];
  const float* b2 = (const float*)d_in[7];
  const float* Wsk = (const float*)d_in[8];
  const float* gsk = (const float*)d_in[9];
  const float* bsk = (const float*)d_in[10];

  char* ws = (char*)d_ws;
  auto align = [](size_t x) { return (x + 255) & ~(size_t)255; };
  size_t off = 0;
  float* stats = (float*)(ws + off);
  off = align(off + 12 * 128 * 4);
  unsigned short* w1p = (unsigned short*)(ws + off);
  off = align(off + (size_t)27 * 2 * 8 * 64 * 8 * 2);
  unsigned short* w2p = (unsigned short*)(ws + off);
  off = align(off + (size_t)27 * 4 * 8 * 64 * 8 * 2);
  unsigned short* wskp = (unsigned short*)(ws + off);
  off = align(off + (size_t)2 * 8 * 64 * 8 * 2);
  unsigned short* fbf = (unsigned short*)(ws + off);
  off = align(off + (size_t)(NV + 1) * 64 * 2);
  unsigned short* c1 = (unsigned short*)(ws + off);
  off = align(off + (size_t)NV * 128 * 2);
  unsigned short* skr = (unsigned short*)(ws + off);
  off = align(off + (size_t)NV * 128 * 2);
  unsigned short* hbf = (unsigned short*)(ws + off);
  off = align(off + (size_t)(NV + 1) * 128 * 2);

  float* out = (float*)d_out;

  zero_stats<<<3, 256, 0, stream>>>(stats);
  const int t1 = 27 * 2 * 8 * 64 * 8;
  pack_w_kernel<<<(t1 + 255) / 256, 256, 0, stream>>>(W1, w1p, 1, t1);
  const int t2 = 27 * 4 * 8 * 64 * 8;
  pack_w_kernel<<<(t2 + 255) / 256, 256, 0, stream>>>(W2, w2p, 2, t2);
  const int t3 = 2 * 8 * 64 * 8;
  pack_w_kernel<<<(t3 + 255) / 256, 256, 0, stream>>>(Wsk, wskp, 1, t3);
  feats_to_bf16<<<((NV + 1) * 16 + 255) / 256, 256, 0, stream>>>(feats, fbf);

  const int convBlocks = (NV + 255) / 256;
  conv_mfma<64, 27, true, unsigned short>
      <<<convBlocks, 256, 0, stream>>>(fbf, nbr, w1p, c1, stats + 0, stats + 128);
  conv_mfma<64, 1, false, unsigned short>
      <<<convBlocks, 256, 0, stream>>>(fbf, nullptr, wskp, skr, stats + 256, stats + 384);
  finalize1<<<1, 256, 0, stream>>>(stats, g1, b1, gsk, bsk);
  bn_to_bf16<<<((NV + 1) * 32 + 255) / 256, 256, 0, stream>>>(c1, stats + 768,
                                                              stats + 896, hbf);
  conv_mfma<128, 27, true, float>
      <<<convBlocks, 256, 0, stream>>>(hbf, nbr, w2p, out, stats + 512, stats + 640);
  finalize2<<<1, 128, 0, stream>>>(stats, g2, b2);
  final_kernel<<<(NV * 32 + 255) / 256, 256, 0, stream>>>(out, skr, stats);
}

// Round 3
// 521.982 us; speedup vs baseline: 1.3892x; 1.3892x over previous
//
#include <hip/hip_runtime.h>
#include <stdint.h>

#define NV 200000
#define BN_EPS 1e-5f

typedef short bf16x8 __attribute__((ext_vector_type(8)));
typedef float f32x4 __attribute__((ext_vector_type(4)));

__device__ inline unsigned short f2bf(float x) {
  union { float f; uint32_t u; } c; c.f = x;
  uint32_t r = c.u + 0x7fffu + ((c.u >> 16) & 1u);
  return (unsigned short)(r >> 16);
}
__device__ inline float bf2f(unsigned short u) {
  union { uint32_t u; float f; } c; c.u = ((uint32_t)u) << 16;
  return c.f;
}

__device__ inline void gload_lds16(const void* g, void* l) {
  __builtin_amdgcn_global_load_lds(
      (const __attribute__((address_space(1))) unsigned int*)(g),
      (__attribute__((address_space(3))) unsigned int*)(l), 16, 0, 0);
}

// ---------------------------------------------------------------------------
// Gather-GEMM with MFMA, software-pipelined:
//   - W tap double-buffered in LDS (stage t+1 during compute of t)
//   - all A gather fragments for tap t prefetched into registers up front
//   - nbr indices for tap t+1 prefetched during compute of t
// A is (NV+1) x K bf16 (row NV = zero sentinel).
// Wpack layout: [NTAPS][K/32][8 colfrag][64 lane][8] bf16 (fragment-native).
// Accumulates per-column sum/sumsq for BN via atomics.
// OUTBF: write bf16 (else fp32).
// ---------------------------------------------------------------------------
template <int K, int NTAPS, bool GATHER, bool OUTBF>
__global__ __launch_bounds__(256, 2) void conv_mfma(
    const unsigned short* __restrict__ Apad, const int* __restrict__ nbr,
    const unsigned short* __restrict__ Wpack, void* __restrict__ outp,
    float* __restrict__ ssum, float* __restrict__ ssq) {
  constexpr int S = K / 32;
  constexpr int TAPH = S * 8 * 64 * 8;   // halfwords per tap
  constexpr int TAPBYTES = TAPH * 2;     // 16KB (K=64) / 32KB (K=128)
  __shared__ unsigned short Wlds[2][TAPH];
  __shared__ float sred[4][128];

  const int tid = threadIdx.x;
  const int w = tid >> 6;
  const int l = tid & 63;
  const int l15 = l & 15;
  const int lhi = l >> 4;
  const int rowbase = blockIdx.x * 256 + w * 64;

  f32x4 acc[4][8];
#pragma unroll
  for (int rf = 0; rf < 4; ++rf)
#pragma unroll
    for (int cf = 0; cf < 8; ++cf) acc[rf][cf] = f32x4{0.f, 0.f, 0.f, 0.f};

  // ---- prologue: stage tap 0 into buf 0; load tap-0 indices ----
  {
    const char* wsrc = (const char*)Wpack;
    const int base = w * (TAPBYTES / 4);
#pragma unroll
    for (int i = 0; i < TAPBYTES / 4096; ++i) {
      const int off = base + i * 1024;
      gload_lds16(wsrc + off + l * 16, (char*)(&Wlds[0][0]) + off);
    }
  }
  int ridx[4];
#pragma unroll
  for (int rf = 0; rf < 4; ++rf) {
    const int row = rowbase + rf * 16 + l15;
    int r = NV;
    if (row < NV) r = GATHER ? nbr[row] : row;
    ridx[rf] = r;
  }
  __syncthreads();  // buf0 staged (vmcnt drained by barrier semantics)

  for (int t = 0; t < NTAPS; ++t) {
    const int cur = t & 1;

    // 1) issue ALL A gather loads for this tap (independent, back-to-back)
    bf16x8 areg[4][S];
#pragma unroll
    for (int rf = 0; rf < 4; ++rf) {
      const unsigned short* ap = Apad + (size_t)ridx[rf] * K + lhi * 8;
#pragma unroll
      for (int s = 0; s < S; ++s)
        areg[rf][s] = *(const bf16x8*)(ap + s * 32);
    }

    // 2) stage next tap's W into the other LDS buffer
    if (t + 1 < NTAPS) {
      const char* wsrc = (const char*)Wpack + (size_t)(t + 1) * TAPBYTES;
      const int base = w * (TAPBYTES / 4);
#pragma unroll
      for (int i = 0; i < TAPBYTES / 4096; ++i) {
        const int off = base + i * 1024;
        gload_lds16(wsrc + off + l * 16, (char*)(&Wlds[cur ^ 1][0]) + off);
      }
    }

    // 3) prefetch next tap's neighbor indices
    int nr[4];
    if (GATHER && (t + 1 < NTAPS)) {
#pragma unroll
      for (int rf = 0; rf < 4; ++rf) {
        const int row = rowbase + rf * 16 + l15;
        int r = NV;
        if (row < NV) r = nbr[(size_t)(t + 1) * NV + row];
        nr[rf] = r;
      }
    }

    // 4) compute: B fragments from LDS, A from prefetched regs
    __builtin_amdgcn_s_setprio(1);
#pragma unroll
    for (int s = 0; s < S; ++s) {
      bf16x8 b[8];
#pragma unroll
      for (int cf = 0; cf < 8; ++cf)
        b[cf] = *(const bf16x8*)&Wlds[cur][((s * 8 + cf) * 64 + l) * 8];
#pragma unroll
      for (int rf = 0; rf < 4; ++rf)
#pragma unroll
        for (int cf = 0; cf < 8; ++cf)
          acc[rf][cf] = __builtin_amdgcn_mfma_f32_16x16x32_bf16(
              areg[rf][s], b[cf], acc[rf][cf], 0, 0, 0);
    }
    __builtin_amdgcn_s_setprio(0);

    __syncthreads();  // next buffer staged; all reads of cur done

    if (GATHER && (t + 1 < NTAPS)) {
#pragma unroll
      for (int rf = 0; rf < 4; ++rf) ridx[rf] = nr[rf];
    }
  }

  // ---- per-column BN statistics (sentinel rows contribute exact zeros) ----
  float psum[8], psq[8];
#pragma unroll
  for (int cf = 0; cf < 8; ++cf) {
    float s = 0.f, q = 0.f;
#pragma unroll
    for (int rf = 0; rf < 4; ++rf)
#pragma unroll
      for (int v = 0; v < 4; ++v) {
        const float x = acc[rf][cf][v];
        s += x;
        q += x * x;
      }
    psum[cf] = s;
    psq[cf] = q;
  }
#pragma unroll
  for (int cf = 0; cf < 8; ++cf) {
    psum[cf] += __shfl_xor(psum[cf], 16);
    psum[cf] += __shfl_xor(psum[cf], 32);
    psq[cf] += __shfl_xor(psq[cf], 16);
    psq[cf] += __shfl_xor(psq[cf], 32);
  }
  if (l < 16) {
#pragma unroll
    for (int cf = 0; cf < 8; ++cf) sred[w][cf * 16 + l] = psum[cf];
  }
  __syncthreads();
  if (tid < 128)
    atomicAdd(&ssum[tid], sred[0][tid] + sred[1][tid] + sred[2][tid] + sred[3][tid]);
  __syncthreads();
  if (l < 16) {
#pragma unroll
    for (int cf = 0; cf < 8; ++cf) sred[w][cf * 16 + l] = psq[cf];
  }
  __syncthreads();
  if (tid < 128)
    atomicAdd(&ssq[tid], sred[0][tid] + sred[1][tid] + sred[2][tid] + sred[3][tid]);

  // ---- store raw conv output ----
#pragma unroll
  for (int rf = 0; rf < 4; ++rf) {
#pragma unroll
    for (int v = 0; v < 4; ++v) {
      const int row = rowbase + rf * 16 + lhi * 4 + v;
      if (row < NV) {
#pragma unroll
        for (int cf = 0; cf < 8; ++cf) {
          const float x = acc[rf][cf][v];
          if (OUTBF)
            ((unsigned short*)outp)[(size_t)row * 128 + cf * 16 + l15] = f2bf(x);
          else
            ((float*)outp)[(size_t)row * 128 + cf * 16 + l15] = x;
        }
      }
    }
  }
}

// ---------------------------------------------------------------------------
// Weight packing: W [taps][K][128] fp32 -> fragment-native bf16 pack.
// dest e = (((tap*S + s)*8 + cf)*64 + l)*8 + j
// src  = W[tap][s*32 + (l>>4)*8 + j][cf*16 + (l&15)]
// ---------------------------------------------------------------------------
__global__ void pack_w_kernel(const float* __restrict__ W,
                              unsigned short* __restrict__ o, int sshift,
                              int total) {
  const int e = blockIdx.x * blockDim.x + threadIdx.x;
  if (e >= total) return;
  const int j = e & 7;
  const int l = (e >> 3) & 63;
  const int cf = (e >> 9) & 7;
  const int ts = e >> 12;
  const int S = 1 << sshift;
  const int s = ts & (S - 1);
  const int tap = ts >> sshift;
  const int kk = s * 32 + (l >> 4) * 8 + j;
  const int col = cf * 16 + (l & 15);
  o[e] = f2bf(W[((size_t)tap * (S * 32) + kk) * 128 + col]);
}

__global__ void feats_to_bf16(const float* __restrict__ f,
                              unsigned short* __restrict__ o) {
  const int i = blockIdx.x * blockDim.x + threadIdx.x;  // (NV+1)*16 vec4 groups
  if (i >= (NV + 1) * 16) return;
  const int row = i >> 4;
  const int c = (i & 15) * 4;
  ushort4 ov;
  if (row < NV) {
    const float4 v = *(const float4*)(f + (size_t)row * 64 + c);
    ov.x = f2bf(v.x);
    ov.y = f2bf(v.y);
    ov.z = f2bf(v.z);
    ov.w = f2bf(v.w);
  } else {
    ov = make_ushort4(0, 0, 0, 0);
  }
  *(ushort4*)(o + (size_t)row * 64 + c) = ov;
}

__global__ void zero_stats(float* st) {
  const int t = blockIdx.x * 256 + threadIdx.x;
  if (t < 768) st[t] = 0.f;
}

// stats layout (floats): 0 s1sum | 128 s1sq | 256 sksum | 384 sksq
//                        512 s2sum | 640 s2sq | 768 sc1 | 896 bi1
//                        1024 scsk | 1152 bisk | 1280 sc2 | 1408 bi2
__global__ void finalize1(float* st, const float* g1, const float* b1,
                          const float* gsk, const float* bsk) {
  const float invN = 1.0f / NV;
  const int t = threadIdx.x;
  if (t < 128) {
    const float m = st[t] * invN;
    const float v = st[128 + t] * invN - m * m;
    const float sc = g1[t] * rsqrtf(v + BN_EPS);
    st[768 + t] = sc;
    st[896 + t] = b1[t] - m * sc;
  } else {
    const int c = t - 128;
    const float m = st[256 + c] * invN;
    const float v = st[384 + c] * invN - m * m;
    const float sc = gsk[c] * rsqrtf(v + BN_EPS);
    st[1024 + c] = sc;
    st[1152 + c] = bsk[c] - m * sc;
  }
}

__global__ void finalize2(float* st, const float* g2, const float* b2) {
  const float invN = 1.0f / NV;
  const int c = threadIdx.x;
  const float m = st[512 + c] * invN;
  const float v = st[640 + c] * invN - m * m;
  const float sc = g2[c] * rsqrtf(v + BN_EPS);
  st[1280 + c] = sc;
  st[1408 + c] = b2[c] - m * sc;
}

__global__ void bn_to_bf16(const unsigned short* __restrict__ raw,
                           const float* __restrict__ scale,
                           const float* __restrict__ bias,
                           unsigned short* __restrict__ outp) {
  const int i = blockIdx.x * blockDim.x + threadIdx.x;  // (NV+1)*32
  if (i >= (NV + 1) * 32) return;
  const int row = i >> 5;
  const int c = (i & 31) * 4;
  ushort4 ov;
  if (row < NV) {
    const ushort4 rv = *(const ushort4*)(raw + (size_t)row * 128 + c);
    ov.x = f2bf(bf2f(rv.x) * scale[c + 0] + bias[c + 0]);
    ov.y = f2bf(bf2f(rv.y) * scale[c + 1] + bias[c + 1]);
    ov.z = f2bf(bf2f(rv.z) * scale[c + 2] + bias[c + 2]);
    ov.w = f2bf(bf2f(rv.w) * scale[c + 3] + bias[c + 3]);
  } else {
    ov = make_ushort4(0, 0, 0, 0);  // sentinel row for conv2 gathers
  }
  *(ushort4*)(outp + (size_t)row * 128 + c) = ov;
}

__global__ void final_kernel(float* __restrict__ outp,
                             const unsigned short* __restrict__ c2,
                             const unsigned short* __restrict__ sk,
                             const float* __restrict__ st) {
  const int i = blockIdx.x * blockDim.x + threadIdx.x;  // NV*32
  if (i >= NV * 32) return;
  const int row = i >> 5;
  const int c = (i & 31) * 4;
  const float* s2 = st + 1280;
  const float* b2 = st + 1408;
  const float* ss = st + 1024;
  const float* bs = st + 1152;
  const ushort4 rv = *(const ushort4*)(c2 + (size_t)row * 128 + c);
  const ushort4 kv = *(const ushort4*)(sk + (size_t)row * 128 + c);
  float4 o;
  o.x = fmaxf(0.f, bf2f(rv.x) * s2[c + 0] + b2[c + 0] + bf2f(kv.x) * ss[c + 0] + bs[c + 0]);
  o.y = fmaxf(0.f, bf2f(rv.y) * s2[c + 1] + b2[c + 1] + bf2f(kv.y) * ss[c + 1] + bs[c + 1]);
  o.z = fmaxf(0.f, bf2f(rv.z) * s2[c + 2] + b2[c + 2] + bf2f(kv.z) * ss[c + 2] + bs[c + 2]);
  o.w = fmaxf(0.f, bf2f(rv.w) * s2[c + 3] + b2[c + 3] + bf2f(kv.w) * ss[c + 3] + bs[c + 3]);
  *(float4*)(outp + (size_t)row * 128 + c) = o;
}

extern "C" void kernel_launch(void* const* d_in, const int* in_sizes, int n_in,
                              void* d_out, int out_size, void* d_ws,
                              size_t ws_size, hipStream_t stream) {
  const float* feats = (const float*)d_in[0];
  const int* nbr = (const int*)d_in[1];
  const float* W1 = (const float*)d_in[2];
  const float* g1 = (const float*)d_in[3];
  const float* b1 = (const float*)d_in[4];
  const float* W2 = (const float*)d_in[5];
  const float* g2 = (const float*)d_in[6];
  const float* b2 = (const float*)d_in[7];
  const float* Wsk = (const float*)d_in[8];
  const float* gsk = (const float*)d_in[9];
  const float* bsk = (const float*)d_in[10];

  char* ws = (char*)d_ws;
  auto align = [](size_t x) { return (x + 255) & ~(size_t)255; };
  size_t off = 0;
  float* stats = (float*)(ws + off);
  off = align(off + 12 * 128 * 4);
  unsigned short* w1p = (unsigned short*)(ws + off);
  off = align(off + (size_t)27 * 2 * 8 * 64 * 8 * 2);
  unsigned short* w2p = (unsigned short*)(ws + off);
  off = align(off + (size_t)27 * 4 * 8 * 64 * 8 * 2);
  unsigned short* wskp = (unsigned short*)(ws + off);
  off = align(off + (size_t)2 * 8 * 64 * 8 * 2);
  unsigned short* fbf = (unsigned short*)(ws + off);
  off = align(off + (size_t)(NV + 1) * 64 * 2);
  unsigned short* c1 = (unsigned short*)(ws + off);   // conv1 raw; reused as c2
  off = align(off + (size_t)NV * 128 * 2);
  unsigned short* skr = (unsigned short*)(ws + off);
  off = align(off + (size_t)NV * 128 * 2);
  unsigned short* hbf = (unsigned short*)(ws + off);
  off = align(off + (size_t)(NV + 1) * 128 * 2);

  float* out = (float*)d_out;

  zero_stats<<<3, 256, 0, stream>>>(stats);
  const int t1 = 27 * 2 * 8 * 64 * 8;
  pack_w_kernel<<<(t1 + 255) / 256, 256, 0, stream>>>(W1, w1p, 1, t1);
  const int t2 = 27 * 4 * 8 * 64 * 8;
  pack_w_kernel<<<(t2 + 255) / 256, 256, 0, stream>>>(W2, w2p, 2, t2);
  const int t3 = 2 * 8 * 64 * 8;
  pack_w_kernel<<<(t3 + 255) / 256, 256, 0, stream>>>(Wsk, wskp, 1, t3);
  feats_to_bf16<<<((NV + 1) * 16 + 255) / 256, 256, 0, stream>>>(feats, fbf);

  const int convBlocks = (NV + 255) / 256;
  conv_mfma<64, 27, true, true>
      <<<convBlocks, 256, 0, stream>>>(fbf, nbr, w1p, c1, stats + 0, stats + 128);
  conv_mfma<64, 1, false, true>
      <<<convBlocks, 256, 0, stream>>>(fbf, nullptr, wskp, skr, stats + 256, stats + 384);
  finalize1<<<1, 256, 0, stream>>>(stats, g1, b1, gsk, bsk);
  bn_to_bf16<<<((NV + 1) * 32 + 255) / 256, 256, 0, stream>>>(c1, stats + 768,
                                                              stats + 896, hbf);
  // conv2 writes bf16 into c1's buffer (c1 is dead after bn_to_bf16)
  conv_mfma<128, 27, true, true>
      <<<convBlocks, 256, 0, stream>>>(hbf, nbr, w2p, c1, stats + 512, stats + 640);
  finalize2<<<1, 128, 0, stream>>>(stats, g2, b2);
  final_kernel<<<(NV * 32 + 255) / 256, 256, 0, stream>>>(out, c1, skr, stats);
}